// Round 12
// baseline (187.535 us; speedup 1.0000x reference)
//
#include <hip/hip_runtime.h>

// ---------------------------------------------------------------------------
// DWT autoencoder round trip. Level-2 dwt2+idwt2 cancel exactly -> LL1r==LL1.
//   K0: rearrange conv weights into consumption order
//   K1 (sweep): NO LDS, no barriers. Lane l owns x cols 4l..4l+3 (float4,
//       natively coalesced = 2 DWT column pairs) + a float2 left-tap. Each
//       wave owns (b, half-width, 2 y-rows) and sweeps 5 band rows x 3 ch,
//       FMA-ing each band row into the y accumulator as it's produced.
//   K2: convT4x4 s2 of y -> l1 bands, fused with idwt2(LL1, l1) -> out
// B=32, C=3, H=W=512.
// R11 lesson: channel-split spilled acc to scratch (+65MB writes). R3-R11:
// the stage->barrier->compute skeleton pins k1 at ~60us because the LDS tile
// has ~1x reuse -- staging is pure overhead. Column-mapped register sweep
// removes the round trip entirely.
// ---------------------------------------------------------------------------

#define BB 32

// K0: wd[((ch*3+a)*3+q)*27 + band*9 + o] = 0.5 * dw[o, ch*3+band, a, q]
//     wu[((cin*4+rt*2+ct)*4+di*2+dj)*9+o] = uw[cin, o, 3-di-2rt, 3-dj-2ct]
__global__ __launch_bounds__(256) void k0_rearrange(
    const float* __restrict__ dw, const float* __restrict__ uw,
    float* __restrict__ wd, float* __restrict__ wu)
{
    const int t = threadIdx.x;
    for (int i = t; i < 729; i += 256) {
        const int o    = i % 9;
        const int band = (i / 9) % 3;
        const int q    = (i / 27) % 3;
        const int a    = (i / 81) % 3;
        const int ch   = i / 243;
        wd[i] = 0.5f * dw[o * 81 + (ch * 3 + band) * 9 + a * 3 + q];
    }
    for (int i = t; i < 1296; i += 256) {
        const int o = i % 9; int r = i / 9;
        const int dj = r & 1; const int di = (r >> 1) & 1; r >>= 2;
        const int ct = r & 1; const int rt = (r >> 1) & 1; const int cin = r >> 2;
        wu[i] = uw[cin * 144 + o * 16 + (3 - di - 2 * rt) * 4 + (3 - dj - 2 * ct)];
    }
}

// K1: wave = (b, half, stripe). stripe s owns y rows {2s, 2s+1} and LL1 rows
// 4s..4s+3; lane l owns y col 64*half + l. Band row r needs x rows 2r,2r+1:
// one float4 (cols 4l..4l+3 -> band cols 2l,2l+1) + one float2 (cols
// 4l-2,4l-1 -> band col 2l-1) per row. Contribution table: band row
// r = 4s-1+rr feeds y row s*2+m with tap a = rr-2m (valid 0..2).
__global__ __launch_bounds__(256, 4) void k1_sweep(
    const float* __restrict__ x,     // (B,3,512,512)
    const float* __restrict__ wd,    // reordered (ch,a,q,band,o), x0.5 folded
    const float* __restrict__ db,    // (9)
    float* __restrict__ LL1,         // (B,3,256,256)
    float* __restrict__ y)           // (B,9,128,128)
{
    const int t    = threadIdx.x;
    const int w    = t >> 6;
    const int l    = t & 63;
    const int bid  = blockIdx.x;
    const int swz  = (bid & 7) * 128 + (bid >> 3);   // 1024 blocks, XCD chunks
    const int W    = swz * 4 + w;                    // global wave 0..4095
    const int b    = W >> 7;
    const int rem  = W & 127;
    const int half = rem & 1;
    const int s    = rem >> 1;                       // stripe 0..63
    const int c0   = 256 * half;                     // x col base
    const int xcl  = c0 + 4 * l;                     // float4 col
    const bool lok = !(half == 0 && l == 0);
    const int  xc2 = lok ? (xcl - 2) : 0;            // float2 col (clamped)

    float acc[2][9];
#pragma unroll
    for (int m = 0; m < 2; ++m)
#pragma unroll
        for (int o = 0; o < 9; ++o) acc[m][o] = db[o];

#pragma unroll
    for (int ch = 0; ch < 3; ++ch) {
        const float* xc  = x + ((size_t)b * 3 + ch) * (512 * 512);
        float*       llc = LL1 + ((size_t)b * 3 + ch) * (256 * 256);
        const float* wch = wd + ch * 243;

#pragma unroll
        for (int rr = 0; rr < 5; ++rr) {
            const int  r   = 4 * s - 1 + rr;         // band row
            const bool rok = (r >= 0);               // false only s==0,rr==0
            const int  xr  = rok ? 2 * r : 0;
            const float* p0 = xc + (size_t)xr * 512;
            const float* p1 = p0 + 512;

            float4 A  = *reinterpret_cast<const float4*>(p0 + xcl);
            float2 Ae = *reinterpret_cast<const float2*>(p0 + xc2);
            float4 Bv = *reinterpret_cast<const float4*>(p1 + xcl);
            float2 Be = *reinterpret_cast<const float2*>(p1 + xc2);
            if (!rok) {
                A.x = A.y = A.z = A.w = 0.f; Bv.x = Bv.y = Bv.z = Bv.w = 0.f;
                Ae.x = Ae.y = 0.f; Be.x = Be.y = 0.f;
            }
            if (!lok) { Ae.x = Ae.y = 0.f; Be.x = Be.y = 0.f; }

            // bands at cols 2l-1 (q-tap 0), 2l (1), 2l+1 (2)
            float lh[3], hl[3], hh[3], ll0, ll1;
            {
                const float s0 = Ae.x + Ae.y, d0 = Ae.x - Ae.y;
                const float s1 = Be.x + Be.y, d1 = Be.x - Be.y;
                lh[0] = s0 - s1; hl[0] = d0 + d1; hh[0] = d0 - d1;
            }
            {
                const float s0 = A.x + A.y, d0 = A.x - A.y;
                const float s1 = Bv.x + Bv.y, d1 = Bv.x - Bv.y;
                lh[1] = s0 - s1; hl[1] = d0 + d1; hh[1] = d0 - d1;
                ll0 = (s0 + s1) * 0.5f;
            }
            {
                const float s0 = A.z + A.w, d0 = A.z - A.w;
                const float s1 = Bv.z + Bv.w, d1 = Bv.z - Bv.w;
                lh[2] = s0 - s1; hl[2] = d0 + d1; hh[2] = d0 - d1;
                ll1 = (s0 + s1) * 0.5f;
            }

            // LL1: stripe owns rows 4s..4s+3 (rr>=1); float2, coalesced
            if (rr >= 1) {
                float2 v; v.x = ll0; v.y = ll1;
                *reinterpret_cast<float2*>(
                    llc + (size_t)r * 256 + 128 * half + 2 * l) = v;
            }

            // FMA this band row into affected y rows: a = rr - 2m in [0,2]
#pragma unroll
            for (int m = 0; m < 2; ++m) {
                const int a = rr - 2 * m;
                if (a >= 0 && a <= 2) {
                    const float* wg = wch + a * 81;
#pragma unroll
                    for (int q = 0; q < 3; ++q) {
                        const float* w0 = wg + q * 27;   // 27 consecutive
                        const float vlh = lh[q], vhl = hl[q], vhh = hh[q];
#pragma unroll
                        for (int o = 0; o < 9; ++o) acc[m][o] += vlh * w0[o];
#pragma unroll
                        for (int o = 0; o < 9; ++o) acc[m][o] += vhl * w0[9 + o];
#pragma unroll
                        for (int o = 0; o < 9; ++o) acc[m][o] += vhh * w0[18 + o];
                    }
                }
            }
        }
    }

    // y stores: lane-contiguous dwords (256B per (m,o) across the wave)
    const int J = 64 * half + l;
#pragma unroll
    for (int m = 0; m < 2; ++m)
#pragma unroll
        for (int o = 0; o < 9; ++o)
            y[(((size_t)b * 9 + o) * 128 + (2 * s + m)) * 128 + J] = acc[m][o];
}

// K2: one block = one batch image, a 32x32 tile at 256-res (=> 64x64 output
// pixels at 512-res), all 3 colors. Each thread owns a 2x2 parity quad; all
// 36 accumulators live (needs VGPR room -> launch_bounds(256,4)).
__global__ __launch_bounds__(256, 4) void k2_up_idwt(
    const float* __restrict__ yg,    // (B,9,128,128)
    const float* __restrict__ wu,    // reordered (cin,rt,ct,di,dj,o)
    const float* __restrict__ ub,    // (9)
    const float* __restrict__ LL1,   // (B,3,256,256)
    float* __restrict__ out)         // (B,3,512,512)
{
    __shared__ float ysh[9][18][19];

    const int t    = threadIdx.x;
    const int b    = blockIdx.x >> 6;
    const int tile = blockIdx.x & 63;
    const int r0   = (tile >> 3) << 5;  // 256-res tile origin
    const int c0   = (tile & 7) << 5;
    const int p0   = (r0 >> 1) - 1;     // y row of local 0
    const int q0   = (c0 >> 1) - 1;

    // ---- stage y tile (18x18 halo, 9 ch) into LDS ----
    for (int item = t; item < 9 * 324; item += 256) {
        const int cin = item / 324;
        int rem       = item - cin * 324;
        const int lp  = rem / 18;
        const int lq  = rem - lp * 18;
        const int p   = p0 + lp, q = q0 + lq;
        float v = 0.f;
        if (p >= 0 && p < 128 && q >= 0 && q < 128)
            v = yg[(((size_t)b * 9 + cin) * 128 + p) * 128 + q];
        ysh[cin][lp][lq] = v;
    }
    __syncthreads();

    const int i2 = t >> 4;   // 0..15
    const int j2 = t & 15;   // 0..15

    float acc[2][2][9];      // [di][dj][out-ch]
#pragma unroll
    for (int di = 0; di < 2; ++di)
#pragma unroll
        for (int dj = 0; dj < 2; ++dj)
#pragma unroll
            for (int o = 0; o < 9; ++o) acc[di][dj][o] = ub[o];

    for (int cin = 0; cin < 9; ++cin) {
        float yv[3][3];
#pragma unroll
        for (int r = 0; r < 3; ++r)
#pragma unroll
            for (int c = 0; c < 3; ++c)
                yv[r][c] = ysh[cin][i2 + r][j2 + c];
        const float* wc = wu + cin * 144;
#pragma unroll
        for (int rt = 0; rt < 2; ++rt)
#pragma unroll
            for (int ct = 0; ct < 2; ++ct) {
                const float* wg = wc + (rt * 2 + ct) * 36;  // 36 consecutive
#pragma unroll
                for (int di = 0; di < 2; ++di)
#pragma unroll
                    for (int dj = 0; dj < 2; ++dj) {
                        const float vv = yv[di + rt][dj + ct];
                        const float* w9 = wg + (di * 2 + dj) * 9;
#pragma unroll
                        for (int o = 0; o < 9; ++o)
                            acc[di][dj][o] += vv * w9[o];
                    }
            }
    }

    // ---- epilogue: idwt2(LL1, LH, HL, HH) -> 4x4 output pixels / color ----
#pragma unroll
    for (int cc = 0; cc < 3; ++cc) {
#pragma unroll
        for (int di = 0; di < 2; ++di) {
            const int I = r0 + 2 * i2 + di;
            const int J = c0 + 2 * j2;
            const float2 llv = *reinterpret_cast<const float2*>(
                LL1 + (((size_t)b * 3 + cc) * 256 + I) * 256 + J);
            float4 top, bot;
            {
                const float ll = llv.x;
                const float lh = acc[di][0][cc * 3 + 0];
                const float hl = acc[di][0][cc * 3 + 1];
                const float hh = acc[di][0][cc * 3 + 2];
                const float e0 = ll + lh, od0 = ll - lh;
                const float e1 = hl + hh, od1 = hl - hh;
                top.x = (e0 + e1) * 0.5f; top.y = (e0 - e1) * 0.5f;
                bot.x = (od0 + od1) * 0.5f; bot.y = (od0 - od1) * 0.5f;
            }
            {
                const float ll = llv.y;
                const float lh = acc[di][1][cc * 3 + 0];
                const float hl = acc[di][1][cc * 3 + 1];
                const float hh = acc[di][1][cc * 3 + 2];
                const float e0 = ll + lh, od0 = ll - lh;
                const float e1 = hl + hh, od1 = hl - hh;
                top.z = (e0 + e1) * 0.5f; top.w = (e0 - e1) * 0.5f;
                bot.z = (od0 + od1) * 0.5f; bot.w = (od0 - od1) * 0.5f;
            }
            float* op = out + (((size_t)b * 3 + cc) * 512 + 2 * I) * 512 + 2 * J;
            *reinterpret_cast<float4*>(op) = top;
            *reinterpret_cast<float4*>(op + 512) = bot;
        }
    }
}

extern "C" void kernel_launch(void* const* d_in, const int* in_sizes, int n_in,
                              void* d_out, int out_size, void* d_ws, size_t ws_size,
                              hipStream_t stream) {
    const float* x  = (const float*)d_in[0];
    const float* dw = (const float*)d_in[1];
    const float* db = (const float*)d_in[2];
    const float* uw = (const float*)d_in[3];
    const float* ub = (const float*)d_in[4];
    float* outp = (float*)d_out;

    float* wsf = (float*)d_ws;
    float* wd  = wsf;            // 729 floats (pad to 768)
    float* wu  = wsf + 768;      // 1296 floats
    float* LL1 = wsf + 2304;                         // 25.2 MB
    float* y   = LL1 + (size_t)BB * 3 * 256 * 256;   // 18.9 MB

    k0_rearrange<<<dim3(1), dim3(256), 0, stream>>>(dw, uw, wd, wu);
    k1_sweep<<<dim3(1024), dim3(256), 0, stream>>>(x, wd, db, LL1, y);
    k2_up_idwt<<<dim3(BB * 64), dim3(256), 0, stream>>>(y, wu, ub, LL1, outp);
}

// Round 13
// 87.850 us; speedup vs baseline: 2.1347x; 2.1347x over previous
//
#include <hip/hip_runtime.h>

// ---------------------------------------------------------------------------
// DWT autoencoder round trip. Level-2 dwt2+idwt2 cancel exactly -> LL1r==LL1.
//   K0: rearrange conv weights into consumption order + zero-page
//   K1: R9's verified one-shot gload_lds structure, but 8x16 y-tile
//       (36.9KB LDS -> 4 blocks/CU, 2x waves/CU) with outputs split across
//       wave-pairs (og=0: o0-4, og=1: o5-8; disjoint, no reduction).
//   K2: convT4x4 s2 of y -> l1 bands, fused with idwt2(LL1, l1) -> out
// B=32, C=3, H=W=512.
// R12 lesson: big per-thread unrolled state spills (VGPR 64 + 160MB scratch
// writes). R9-R12 lesson: k1 is overlap-starved at 2 blocks/CU; shrink LDS
// to 36.9KB for 4 blocks/CU while keeping the verified math byte-identical.
// ---------------------------------------------------------------------------

#define BB 32

// K0: wd[((ch*3+a)*3+q)*27 + band*9 + o] = 0.5 * dw[o, ch*3+band, a, q]
//     wu[((cin*4+rt*2+ct)*4+di*2+dj)*9+o] = uw[cin, o, 3-di-2rt, 3-dj-2ct]
//     zp[0..15] = 0 (zero-page for invalid gload lanes)
__global__ __launch_bounds__(256) void k0_rearrange(
    const float* __restrict__ dw, const float* __restrict__ uw,
    float* __restrict__ wd, float* __restrict__ wu, float* __restrict__ zp)
{
    const int t = threadIdx.x;
    for (int i = t; i < 729; i += 256) {
        const int o    = i % 9;
        const int band = (i / 9) % 3;
        const int q    = (i / 27) % 3;
        const int a    = (i / 81) % 3;
        const int ch   = i / 243;
        wd[i] = 0.5f * dw[o * 81 + (ch * 3 + band) * 9 + a * 3 + q];
    }
    for (int i = t; i < 1296; i += 256) {
        const int o = i % 9; int r = i / 9;
        const int dj = r & 1; const int di = (r >> 1) & 1; r >>= 2;
        const int ct = r & 1; const int rt = (r >> 1) & 1; const int cin = r >> 2;
        wu[i] = uw[cin * 144 + o * 16 + (3 - di - 2 * rt) * 4 + (3 - dj - 2 * ct)];
    }
    if (t < 16) zp[t] = 0.f;
}

__device__ __forceinline__ void gload16(const float* gp, float* lp) {
    __builtin_amdgcn_global_load_lds(
        (const __attribute__((address_space(1))) void*)gp,
        (__attribute__((address_space(3))) void*)lp, 16, 0, 0);
}

// K1: block = 8x16 y-tile. x tile per ch = 34 rows x 17 float4 = 578 slots,
// padded to 768 (3 full-wave gload rounds; invalid lanes read the zero-page,
// junk lands in pad slots never read). 256 threads = 2 og-groups x 128:
// og=0 computes outputs 0-4 (+ LL1 writes), og=1 computes outputs 5-8.
__global__ __launch_bounds__(256, 4) void k1_dwt_down(
    const float* __restrict__ x,     // (B,3,512,512)
    const float* __restrict__ wd,    // reordered (ch,a,q,band,o), x0.5 folded
    const float* __restrict__ db,    // (9)
    const float* __restrict__ zp,    // 16-float zero page
    float* __restrict__ LL1,         // (B,3,256,256)
    float* __restrict__ y)           // (B,9,128,128)
{
    __shared__ float xs[3 * 3072];   // 3 ch x 768 f4 slots = 36.86 KB

    const int t    = threadIdx.x;
    const int bid  = blockIdx.x;                     // 0..4095
    const int swz  = (bid & 7) * 512 + (bid >> 3);   // XCD-contiguous chunks
    const int b    = swz >> 7;                       // image
    const int tin  = swz & 127;                      // tile within image
    const int I0   = (tin >> 3) * 8;                 // y row origin (0..120)
    const int J0   = (tin & 7) * 16;                 // y col origin (0..112)
    const int gr0  = 4 * I0 - 2;                     // x row of LDS row 0
    const int gc0  = 4 * J0 - 4;                     // x col of LDS col 0

    // ---- one-shot stage: 3 ch x 3 full-wave gload rounds ----
#pragma unroll
    for (int ch = 0; ch < 3; ++ch) {
        const float* xc = x + ((size_t)b * 3 + ch) * (512 * 512);
#pragma unroll
        for (int n = 0; n < 3; ++n) {
            const int idx = n * 256 + t;      // slot within channel, 0..767
            const int lr  = idx / 17;
            const int f4c = idx - lr * 17;
            const int gr  = gr0 + lr;
            const bool ok = (idx < 578) && (gr >= 0) && !(f4c == 0 && J0 == 0);
            const float* gp = ok ? (xc + (size_t)gr * 512 + gc0 + 4 * f4c) : zp;
            gload16(gp, &xs[(ch * 768 + idx) * 4]);
        }
    }

    const int og = t >> 7;           // output group: 0 -> o0..4, 1 -> o5..8
    const int tl = t & 127;
    const int ti = tl >> 4;          // 0..7
    const int tj = tl & 15;          // 0..15
    const int I  = I0 + ti;
    const int J  = J0 + tj;

    float acc[5];
    if (og == 0) {
#pragma unroll
        for (int o = 0; o < 5; ++o) acc[o] = db[o];
    } else {
#pragma unroll
        for (int o = 0; o < 4; ++o) acc[o] = db[5 + o];
        acc[4] = 0.f;
    }

    __syncthreads();                 // all three channels staged

#pragma unroll
    for (int ch = 0; ch < 3; ++ch) {
        const float* xb  = xs + ch * 3072;
        const float* wch = wd + ch * 243;
        float* llc = LL1 + ((size_t)b * 3 + ch) * (256 * 256);

#pragma unroll
        for (int a = 0; a < 3; ++a) {
            float2 p[2][3];                   // [x-row parity][band-col tap]
#pragma unroll
            for (int rr = 0; rr < 2; ++rr)
#pragma unroll
                for (int k = 0; k < 3; ++k)
                    p[rr][k] = *reinterpret_cast<const float2*>(
                        &xb[(4 * ti + 2 * a + rr) * 68 + 4 * tj + 2 + 2 * k]);

            float lh[3], hl[3], hh[3], llv1, llv2;
            {
                const float s0 = p[0][0].x + p[0][0].y, d0 = p[0][0].x - p[0][0].y;
                const float s1 = p[1][0].x + p[1][0].y, d1 = p[1][0].x - p[1][0].y;
                lh[0] = s0 - s1; hl[0] = d0 + d1; hh[0] = d0 - d1;
            }
            {
                const float s0 = p[0][1].x + p[0][1].y, d0 = p[0][1].x - p[0][1].y;
                const float s1 = p[1][1].x + p[1][1].y, d1 = p[1][1].x - p[1][1].y;
                lh[1] = s0 - s1; hl[1] = d0 + d1; hh[1] = d0 - d1;
                llv1 = (s0 + s1) * 0.5f;
            }
            {
                const float s0 = p[0][2].x + p[0][2].y, d0 = p[0][2].x - p[0][2].y;
                const float s1 = p[1][2].x + p[1][2].y, d1 = p[1][2].x - p[1][2].y;
                lh[2] = s0 - s1; hl[2] = d0 + d1; hh[2] = d0 - d1;
                llv2 = (s0 + s1) * 0.5f;
            }

            // LL1 (og0 only): level-1 row r=2I-1+a (a>=1), cols {2J, 2J+1}
            if (og == 0 && a >= 1) {
                float2 w2; w2.x = llv1; w2.y = llv2;
                *reinterpret_cast<float2*>(llc + (size_t)(2 * I - 1 + a) * 256 + 2 * J) = w2;
            }

            const float* wg = wch + a * 81;
#pragma unroll
            for (int q = 0; q < 3; ++q) {
                const float* w0 = wg + q * 27;   // 27 consecutive uniform weights
                const float vlh = lh[q], vhl = hl[q], vhh = hh[q];
                if (og == 0) {                   // wave-uniform branch
#pragma unroll
                    for (int o = 0; o < 5; ++o) acc[o] += vlh * w0[o];
#pragma unroll
                    for (int o = 0; o < 5; ++o) acc[o] += vhl * w0[9 + o];
#pragma unroll
                    for (int o = 0; o < 5; ++o) acc[o] += vhh * w0[18 + o];
                } else {
#pragma unroll
                    for (int o = 0; o < 4; ++o) acc[o] += vlh * w0[5 + o];
#pragma unroll
                    for (int o = 0; o < 4; ++o) acc[o] += vhl * w0[14 + o];
#pragma unroll
                    for (int o = 0; o < 4; ++o) acc[o] += vhh * w0[23 + o];
                }
            }
        }
    }

    if (og == 0) {
#pragma unroll
        for (int o = 0; o < 5; ++o)
            y[(((size_t)b * 9 + o) * 128 + I) * 128 + J] = acc[o];
    } else {
#pragma unroll
        for (int o = 0; o < 4; ++o)
            y[(((size_t)b * 9 + 5 + o) * 128 + I) * 128 + J] = acc[o];
    }
}

// K2: one block = one batch image, a 32x32 tile at 256-res (=> 64x64 output
// pixels at 512-res), all 3 colors. Each thread owns a 2x2 parity quad; all
// 36 accumulators live (needs VGPR room -> launch_bounds(256,4)).
__global__ __launch_bounds__(256, 4) void k2_up_idwt(
    const float* __restrict__ yg,    // (B,9,128,128)
    const float* __restrict__ wu,    // reordered (cin,rt,ct,di,dj,o)
    const float* __restrict__ ub,    // (9)
    const float* __restrict__ LL1,   // (B,3,256,256)
    float* __restrict__ out)         // (B,3,512,512)
{
    __shared__ float ysh[9][18][19];

    const int t    = threadIdx.x;
    const int b    = blockIdx.x >> 6;
    const int tile = blockIdx.x & 63;
    const int r0   = (tile >> 3) << 5;  // 256-res tile origin
    const int c0   = (tile & 7) << 5;
    const int p0   = (r0 >> 1) - 1;     // y row of local 0
    const int q0   = (c0 >> 1) - 1;

    // ---- stage y tile (18x18 halo, 9 ch) into LDS ----
    for (int item = t; item < 9 * 324; item += 256) {
        const int cin = item / 324;
        int rem       = item - cin * 324;
        const int lp  = rem / 18;
        const int lq  = rem - lp * 18;
        const int p   = p0 + lp, q = q0 + lq;
        float v = 0.f;
        if (p >= 0 && p < 128 && q >= 0 && q < 128)
            v = yg[(((size_t)b * 9 + cin) * 128 + p) * 128 + q];
        ysh[cin][lp][lq] = v;
    }
    __syncthreads();

    const int i2 = t >> 4;   // 0..15
    const int j2 = t & 15;   // 0..15

    float acc[2][2][9];      // [di][dj][out-ch]
#pragma unroll
    for (int di = 0; di < 2; ++di)
#pragma unroll
        for (int dj = 0; dj < 2; ++dj)
#pragma unroll
            for (int o = 0; o < 9; ++o) acc[di][dj][o] = ub[o];

    for (int cin = 0; cin < 9; ++cin) {
        float yv[3][3];
#pragma unroll
        for (int r = 0; r < 3; ++r)
#pragma unroll
            for (int c = 0; c < 3; ++c)
                yv[r][c] = ysh[cin][i2 + r][j2 + c];
        const float* wc = wu + cin * 144;
#pragma unroll
        for (int rt = 0; rt < 2; ++rt)
#pragma unroll
            for (int ct = 0; ct < 2; ++ct) {
                const float* wg = wc + (rt * 2 + ct) * 36;  // 36 consecutive
#pragma unroll
                for (int di = 0; di < 2; ++di)
#pragma unroll
                    for (int dj = 0; dj < 2; ++dj) {
                        const float vv = yv[di + rt][dj + ct];
                        const float* w9 = wg + (di * 2 + dj) * 9;
#pragma unroll
                        for (int o = 0; o < 9; ++o)
                            acc[di][dj][o] += vv * w9[o];
                    }
            }
    }

    // ---- epilogue: idwt2(LL1, LH, HL, HH) -> 4x4 output pixels / color ----
#pragma unroll
    for (int cc = 0; cc < 3; ++cc) {
#pragma unroll
        for (int di = 0; di < 2; ++di) {
            const int I = r0 + 2 * i2 + di;
            const int J = c0 + 2 * j2;
            const float2 llv = *reinterpret_cast<const float2*>(
                LL1 + (((size_t)b * 3 + cc) * 256 + I) * 256 + J);
            float4 top, bot;
            {
                const float ll = llv.x;
                const float lh = acc[di][0][cc * 3 + 0];
                const float hl = acc[di][0][cc * 3 + 1];
                const float hh = acc[di][0][cc * 3 + 2];
                const float e0 = ll + lh, od0 = ll - lh;
                const float e1 = hl + hh, od1 = hl - hh;
                top.x = (e0 + e1) * 0.5f; top.y = (e0 - e1) * 0.5f;
                bot.x = (od0 + od1) * 0.5f; bot.y = (od0 - od1) * 0.5f;
            }
            {
                const float ll = llv.y;
                const float lh = acc[di][1][cc * 3 + 0];
                const float hl = acc[di][1][cc * 3 + 1];
                const float hh = acc[di][1][cc * 3 + 2];
                const float e0 = ll + lh, od0 = ll - lh;
                const float e1 = hl + hh, od1 = hl - hh;
                top.z = (e0 + e1) * 0.5f; top.w = (e0 - e1) * 0.5f;
                bot.z = (od0 + od1) * 0.5f; bot.w = (od0 - od1) * 0.5f;
            }
            float* op = out + (((size_t)b * 3 + cc) * 512 + 2 * I) * 512 + 2 * J;
            *reinterpret_cast<float4*>(op) = top;
            *reinterpret_cast<float4*>(op + 512) = bot;
        }
    }
}

extern "C" void kernel_launch(void* const* d_in, const int* in_sizes, int n_in,
                              void* d_out, int out_size, void* d_ws, size_t ws_size,
                              hipStream_t stream) {
    const float* x  = (const float*)d_in[0];
    const float* dw = (const float*)d_in[1];
    const float* db = (const float*)d_in[2];
    const float* uw = (const float*)d_in[3];
    const float* ub = (const float*)d_in[4];
    float* outp = (float*)d_out;

    float* wsf = (float*)d_ws;
    float* wd  = wsf;            // 729 floats (pad to 768)
    float* wu  = wsf + 768;      // 1296 floats
    float* zp  = wsf + 2240;     // 16-float zero page (16B aligned)
    float* LL1 = wsf + 2304;                         // 25.2 MB
    float* y   = LL1 + (size_t)BB * 3 * 256 * 256;   // 18.9 MB

    k0_rearrange<<<dim3(1), dim3(256), 0, stream>>>(dw, uw, wd, wu, zp);
    k1_dwt_down<<<dim3(4096), dim3(256), 0, stream>>>(x, wd, db, zp, LL1, y);
    k2_up_idwt<<<dim3(BB * 64), dim3(256), 0, stream>>>(y, wu, ub, LL1, outp);
}

// Round 14
// 82.246 us; speedup vs baseline: 2.2802x; 1.0681x over previous
//
#include <hip/hip_runtime.h>

// ---------------------------------------------------------------------------
// DWT autoencoder round trip. Level-2 dwt2+idwt2 cancel exactly -> LL1r==LL1.
//   K0: rearrange conv weights into consumption order + zero-page
//   K1: WAVE-INDEPENDENT dwt+conv. One wave = one 4x16 y-tile; the wave
//       stages exactly the x rows it consumes (15 gload_lds, 14.7KB), does a
//       wave-local s_waitcnt vmcnt(0) -- NO __syncthreads anywhere -- then
//       the verified band+conv math. Waves desync freely; each stalls only
//       on its own loads (kills the block-wide barrier-drain p99 stall that
//       pinned every 60-67us variant).
//   K2: convT4x4 s2 of y -> l1 bands, fused with idwt2(LL1, l1) -> out
// B=32, C=3, H=W=512.
// ---------------------------------------------------------------------------

#define BB 32

// K0: wd[((ch*3+a)*3+q)*27 + band*9 + o] = 0.5 * dw[o, ch*3+band, a, q]
//     wu[((cin*4+rt*2+ct)*4+di*2+dj)*9+o] = uw[cin, o, 3-di-2rt, 3-dj-2ct]
//     zp[0..15] = 0 (zero-page for invalid gload lanes)
__global__ __launch_bounds__(256) void k0_rearrange(
    const float* __restrict__ dw, const float* __restrict__ uw,
    float* __restrict__ wd, float* __restrict__ wu, float* __restrict__ zp)
{
    const int t = threadIdx.x;
    for (int i = t; i < 729; i += 256) {
        const int o    = i % 9;
        const int band = (i / 9) % 3;
        const int q    = (i / 27) % 3;
        const int a    = (i / 81) % 3;
        const int ch   = i / 243;
        wd[i] = 0.5f * dw[o * 81 + (ch * 3 + band) * 9 + a * 3 + q];
    }
    for (int i = t; i < 1296; i += 256) {
        const int o = i % 9; int r = i / 9;
        const int dj = r & 1; const int di = (r >> 1) & 1; r >>= 2;
        const int ct = r & 1; const int rt = (r >> 1) & 1; const int cin = r >> 2;
        wu[i] = uw[cin * 144 + o * 16 + (3 - di - 2 * rt) * 4 + (3 - dj - 2 * ct)];
    }
    if (t < 16) zp[t] = 0.f;
}

__device__ __forceinline__ void gload16(const float* gp, float* lp) {
    __builtin_amdgcn_global_load_lds(
        (const __attribute__((address_space(1))) void*)gp,
        (__attribute__((address_space(3))) void*)lp, 16, 0, 0);
}

// K1: one wave (64 threads) = one 4x16 y-tile. x tile per ch = 18 rows x
// 17 float4 = 306 slots, padded to 320 (5 full-wave gload rounds; invalid
// lanes read the zero-page, junk lands in pad slots never read).
// Lane: ti = lane>>4 (0..3), tj = lane&15. No barriers.
__global__ __launch_bounds__(64) void k1_dwt_down(
    const float* __restrict__ x,     // (B,3,512,512)
    const float* __restrict__ wd,    // reordered (ch,a,q,band,o), x0.5 folded
    const float* __restrict__ db,    // (9)
    const float* __restrict__ zp,    // 16-float zero page
    float* __restrict__ LL1,         // (B,3,256,256)
    float* __restrict__ y)           // (B,9,128,128)
{
    __shared__ float xs[3 * 1280];   // 3 ch x 320 f4 slots = 15.36 KB

    const int lane = threadIdx.x;
    const int bid  = blockIdx.x;                      // 0..8191
    const int swz  = (bid & 7) * 1024 + (bid >> 3);   // XCD-contiguous chunks
    const int b    = swz >> 8;                        // image 0..31
    const int tin  = swz & 255;                       // tile within image
    const int I0   = (tin >> 3) * 4;                  // y row origin (0..124)
    const int J0   = (tin & 7) * 16;                  // y col origin (0..112)
    const int gr0  = 4 * I0 - 2;                      // x row of LDS row 0
    const int gc0  = 4 * J0 - 4;                      // x col of LDS col 0

    // ---- stage: 3 ch x 5 full-wave gload rounds (this wave's rows only) ----
#pragma unroll
    for (int ch = 0; ch < 3; ++ch) {
        const float* xc = x + ((size_t)b * 3 + ch) * (512 * 512);
#pragma unroll
        for (int n = 0; n < 5; ++n) {
            const int idx = n * 64 + lane;    // slot within channel, 0..319
            const int lr  = idx / 17;         // 0..18 (306 used -> lr<=17)
            const int f4c = idx - lr * 17;
            const int gr  = gr0 + lr;
            const bool ok = (idx < 306) && (gr >= 0) && !(f4c == 0 && J0 == 0);
            const float* gp = ok ? (xc + (size_t)gr * 512 + gc0 + 4 * f4c) : zp;
            gload16(gp, &xs[(ch * 320 + idx) * 4]);
        }
    }

    float acc[9];
#pragma unroll
    for (int o = 0; o < 9; ++o) acc[o] = db[o];

    // wave-local drain: this wave's gloads are its own LDS producers
    asm volatile("s_waitcnt vmcnt(0)" ::: "memory");
    __builtin_amdgcn_sched_barrier(0);

    const int ti = lane >> 4;        // 0..3
    const int tj = lane & 15;        // 0..15
    const int I  = I0 + ti;
    const int J  = J0 + tj;

#pragma unroll
    for (int ch = 0; ch < 3; ++ch) {
        const float* xb  = xs + ch * 1280;
        const float* wch = wd + ch * 243;
        float* llc = LL1 + ((size_t)b * 3 + ch) * (256 * 256);

#pragma unroll
        for (int a = 0; a < 3; ++a) {
            float2 p[2][3];                   // [x-row parity][band-col tap]
#pragma unroll
            for (int rr = 0; rr < 2; ++rr)
#pragma unroll
                for (int k = 0; k < 3; ++k)
                    p[rr][k] = *reinterpret_cast<const float2*>(
                        &xb[(4 * ti + 2 * a + rr) * 68 + 4 * tj + 2 + 2 * k]);

            float lh[3], hl[3], hh[3], llv1, llv2;
            {
                const float s0 = p[0][0].x + p[0][0].y, d0 = p[0][0].x - p[0][0].y;
                const float s1 = p[1][0].x + p[1][0].y, d1 = p[1][0].x - p[1][0].y;
                lh[0] = s0 - s1; hl[0] = d0 + d1; hh[0] = d0 - d1;
            }
            {
                const float s0 = p[0][1].x + p[0][1].y, d0 = p[0][1].x - p[0][1].y;
                const float s1 = p[1][1].x + p[1][1].y, d1 = p[1][1].x - p[1][1].y;
                lh[1] = s0 - s1; hl[1] = d0 + d1; hh[1] = d0 - d1;
                llv1 = (s0 + s1) * 0.5f;
            }
            {
                const float s0 = p[0][2].x + p[0][2].y, d0 = p[0][2].x - p[0][2].y;
                const float s1 = p[1][2].x + p[1][2].y, d1 = p[1][2].x - p[1][2].y;
                lh[2] = s0 - s1; hl[2] = d0 + d1; hh[2] = d0 - d1;
                llv2 = (s0 + s1) * 0.5f;
            }

            // LL1: level-1 row r=2I-1+a (a>=1), cols {2J, 2J+1}
            if (a >= 1) {
                float2 w2; w2.x = llv1; w2.y = llv2;
                *reinterpret_cast<float2*>(llc + (size_t)(2 * I - 1 + a) * 256 + 2 * J) = w2;
            }

            const float* wg = wch + a * 81;
#pragma unroll
            for (int q = 0; q < 3; ++q) {
                const float* w0 = wg + q * 27;   // 27 consecutive uniform weights
#pragma unroll
                for (int o = 0; o < 9; ++o) acc[o] += lh[q] * w0[o];
#pragma unroll
                for (int o = 0; o < 9; ++o) acc[o] += hl[q] * w0[9 + o];
#pragma unroll
                for (int o = 0; o < 9; ++o) acc[o] += hh[q] * w0[18 + o];
            }
        }
    }

#pragma unroll
    for (int o = 0; o < 9; ++o)
        y[(((size_t)b * 9 + o) * 128 + I) * 128 + J] = acc[o];
}

// K2: one block = one batch image, a 32x32 tile at 256-res (=> 64x64 output
// pixels at 512-res), all 3 colors. Each thread owns a 2x2 parity quad; all
// 36 accumulators live (needs VGPR room -> launch_bounds(256,4)).
__global__ __launch_bounds__(256, 4) void k2_up_idwt(
    const float* __restrict__ yg,    // (B,9,128,128)
    const float* __restrict__ wu,    // reordered (cin,rt,ct,di,dj,o)
    const float* __restrict__ ub,    // (9)
    const float* __restrict__ LL1,   // (B,3,256,256)
    float* __restrict__ out)         // (B,3,512,512)
{
    __shared__ float ysh[9][18][19];

    const int t    = threadIdx.x;
    const int b    = blockIdx.x >> 6;
    const int tile = blockIdx.x & 63;
    const int r0   = (tile >> 3) << 5;  // 256-res tile origin
    const int c0   = (tile & 7) << 5;
    const int p0   = (r0 >> 1) - 1;     // y row of local 0
    const int q0   = (c0 >> 1) - 1;

    // ---- stage y tile (18x18 halo, 9 ch) into LDS ----
    for (int item = t; item < 9 * 324; item += 256) {
        const int cin = item / 324;
        int rem       = item - cin * 324;
        const int lp  = rem / 18;
        const int lq  = rem - lp * 18;
        const int p   = p0 + lp, q = q0 + lq;
        float v = 0.f;
        if (p >= 0 && p < 128 && q >= 0 && q < 128)
            v = yg[(((size_t)b * 9 + cin) * 128 + p) * 128 + q];
        ysh[cin][lp][lq] = v;
    }
    __syncthreads();

    const int i2 = t >> 4;   // 0..15
    const int j2 = t & 15;   // 0..15

    float acc[2][2][9];      // [di][dj][out-ch]
#pragma unroll
    for (int di = 0; di < 2; ++di)
#pragma unroll
        for (int dj = 0; dj < 2; ++dj)
#pragma unroll
            for (int o = 0; o < 9; ++o) acc[di][dj][o] = ub[o];

    for (int cin = 0; cin < 9; ++cin) {
        float yv[3][3];
#pragma unroll
        for (int r = 0; r < 3; ++r)
#pragma unroll
            for (int c = 0; c < 3; ++c)
                yv[r][c] = ysh[cin][i2 + r][j2 + c];
        const float* wc = wu + cin * 144;
#pragma unroll
        for (int rt = 0; rt < 2; ++rt)
#pragma unroll
            for (int ct = 0; ct < 2; ++ct) {
                const float* wg = wc + (rt * 2 + ct) * 36;  // 36 consecutive
#pragma unroll
                for (int di = 0; di < 2; ++di)
#pragma unroll
                    for (int dj = 0; dj < 2; ++dj) {
                        const float vv = yv[di + rt][dj + ct];
                        const float* w9 = wg + (di * 2 + dj) * 9;
#pragma unroll
                        for (int o = 0; o < 9; ++o)
                            acc[di][dj][o] += vv * w9[o];
                    }
            }
    }

    // ---- epilogue: idwt2(LL1, LH, HL, HH) -> 4x4 output pixels / color ----
#pragma unroll
    for (int cc = 0; cc < 3; ++cc) {
#pragma unroll
        for (int di = 0; di < 2; ++di) {
            const int I = r0 + 2 * i2 + di;
            const int J = c0 + 2 * j2;
            const float2 llv = *reinterpret_cast<const float2*>(
                LL1 + (((size_t)b * 3 + cc) * 256 + I) * 256 + J);
            float4 top, bot;
            {
                const float ll = llv.x;
                const float lh = acc[di][0][cc * 3 + 0];
                const float hl = acc[di][0][cc * 3 + 1];
                const float hh = acc[di][0][cc * 3 + 2];
                const float e0 = ll + lh, od0 = ll - lh;
                const float e1 = hl + hh, od1 = hl - hh;
                top.x = (e0 + e1) * 0.5f; top.y = (e0 - e1) * 0.5f;
                bot.x = (od0 + od1) * 0.5f; bot.y = (od0 - od1) * 0.5f;
            }
            {
                const float ll = llv.y;
                const float lh = acc[di][1][cc * 3 + 0];
                const float hl = acc[di][1][cc * 3 + 1];
                const float hh = acc[di][1][cc * 3 + 2];
                const float e0 = ll + lh, od0 = ll - lh;
                const float e1 = hl + hh, od1 = hl - hh;
                top.z = (e0 + e1) * 0.5f; top.w = (e0 - e1) * 0.5f;
                bot.z = (od0 + od1) * 0.5f; bot.w = (od0 - od1) * 0.5f;
            }
            float* op = out + (((size_t)b * 3 + cc) * 512 + 2 * I) * 512 + 2 * J;
            *reinterpret_cast<float4*>(op) = top;
            *reinterpret_cast<float4*>(op + 512) = bot;
        }
    }
}

extern "C" void kernel_launch(void* const* d_in, const int* in_sizes, int n_in,
                              void* d_out, int out_size, void* d_ws, size_t ws_size,
                              hipStream_t stream) {
    const float* x  = (const float*)d_in[0];
    const float* dw = (const float*)d_in[1];
    const float* db = (const float*)d_in[2];
    const float* uw = (const float*)d_in[3];
    const float* ub = (const float*)d_in[4];
    float* outp = (float*)d_out;

    float* wsf = (float*)d_ws;
    float* wd  = wsf;            // 729 floats (pad to 768)
    float* wu  = wsf + 768;      // 1296 floats
    float* zp  = wsf + 2240;     // 16-float zero page (16B aligned)
    float* LL1 = wsf + 2304;                         // 25.2 MB
    float* y   = LL1 + (size_t)BB * 3 * 256 * 256;   // 18.9 MB

    k0_rearrange<<<dim3(1), dim3(256), 0, stream>>>(dw, uw, wd, wu, zp);
    k1_dwt_down<<<dim3(8192), dim3(64), 0, stream>>>(x, wd, db, zp, LL1, y);
    k2_up_idwt<<<dim3(BB * 64), dim3(256), 0, stream>>>(y, wu, ub, LL1, outp);
}